// Round 5
// baseline (309.939 us; speedup 1.0000x reference)
//
#include <hip/hip_runtime.h>
#include <cstdint>
#include <cstddef>

#define BB 4
#define CC 19
#define HH 512
#define WW 1024
#define HW (HH*WW)          // 524288 = 2^19
#define HW4 (HW/4)          // 131072 = 2^17
#define BHW (BB*HW)
#define KTOP 256
#define EPSF 1e-6f
#define NB1 8192
#define SEG 128
#define LOGC 2.9444389791664403f   // ln(19)

__device__ __forceinline__ unsigned int sortable(float x) {
    unsigned int u = __float_as_uint(x);
    return (u & 0x80000000u) ? ~u : (u | 0x80000000u);
}
__device__ __forceinline__ float unsortable(unsigned int K) {
    unsigned int u = (K & 0x80000000u) ? (K & 0x7FFFFFFFu) : ~K;
    return __uint_as_float(u);
}

// ---------------- Kernel 1: entropy + argmax + zero-init ----------------
__global__ __launch_bounds__(256) void k_ent(const float4* __restrict__ logit,
                                             float4* __restrict__ ent,
                                             uchar4* __restrict__ pred,
                                             unsigned int* __restrict__ histz,
                                             float* __restrict__ outz) {
    int idx = blockIdx.x * 256 + threadIdx.x;     // over BHW/4
    if (idx < 98312) histz[idx] = 0;              // hist1 + hist2 + hsum + scalars
    if (idx < BB) outz[idx] = 0.f;
    int b = idx >> 17;
    int q = idx & (HW4 - 1);
    const float4* base = logit + (size_t)b * CC * HW4 + q;
    float e0 = 0.f, e1 = 0.f, e2 = 0.f, e3 = 0.f;
    float m0 = -1.f, m1 = -1.f, m2 = -1.f, m3 = -1.f;
    int a0 = 0, a1 = 0, a2 = 0, a3 = 0;
#pragma unroll
    for (int c = 0; c < CC; ++c) {
        float4 p = base[(size_t)c * HW4];
        e0 -= p.x * __logf(p.x + EPSF); if (p.x > m0) { m0 = p.x; a0 = c; }
        e1 -= p.y * __logf(p.y + EPSF); if (p.y > m1) { m1 = p.y; a1 = c; }
        e2 -= p.z * __logf(p.z + EPSF); if (p.z > m2) { m2 = p.z; a2 = c; }
        e3 -= p.w * __logf(p.w + EPSF); if (p.w > m3) { m3 = p.w; a3 = c; }
    }
    ent[idx] = make_float4(e0, e1, e2, e3);
    pred[idx] = make_uchar4((unsigned char)a0, (unsigned char)a1,
                            (unsigned char)a2, (unsigned char)a3);
}

// ---------------- Kernel 2: score + wave-aggregated 13-bit histogram ----------------
__global__ __launch_bounds__(256) void k_score_hist(const float* __restrict__ ent,
                                                    const unsigned char* __restrict__ pred,
                                                    float* __restrict__ score,
                                                    unsigned int* __restrict__ hist1) {
    __shared__ unsigned int lh[NB1];
    int b = blockIdx.x >> 7;          // / SEG
    int seg = blockIdx.x & (SEG - 1);
    for (int i = threadIdx.x; i < NB1; i += 256) lh[i] = 0;
    __syncthreads();
    const float* eb = ent + (size_t)b * HW;
    const unsigned char* pb = pred + (size_t)b * HW;
    int base = seg * (HW / SEG);      // 4096 pixels = 4 rows
    int lane = threadIdx.x & 63;

    for (int it = 0; it < 16; ++it) {
        int hw = base + it * 256 + threadIdx.x;
        int h = hw >> 10;
        int w = hw & (WW - 1);

        float es = 0.f;
        int cls[9];
        int nv = 0;
#pragma unroll
        for (int i = 0; i < 9; ++i) {
            int dh = i / 3 - 1, dw = i % 3 - 1;
            int hh = h + dh, ww = w + dw;
            bool ok = (hh >= 0) & (hh < HH) & (ww >= 0) & (ww < WW);
            int o = ok ? ((hh << 10) | ww) : 0;
            es += ok ? eb[o] : 0.f;
            cls[i] = ok ? (int)pb[o] : 255;
            nv += ok ? 1 : 0;
        }
        float inv = 1.f / (float)nv;
        // branch-free impurity: -sum_{distinct c} d_c ln(d_c+eps)
        //                      = -inv * sum_{i valid} ln(cnt_i*inv + eps)
        float lsum = 0.f;
#pragma unroll
        for (int i = 0; i < 9; ++i) {
            int cnt = 0;
#pragma unroll
            for (int j = 0; j < 9; ++j) cnt += (cls[j] == cls[i]) ? 1 : 0;
            float lg = __logf((float)cnt * inv + EPSF);
            lsum += (cls[i] != 255) ? lg : 0.f;
        }
        float imp = -inv * lsum;
        float v = (es * (1.f / (9.f * LOGC))) * (imp * (1.f / LOGC));
        score[(size_t)b * HW + hw] = v;

        // wave-aggregated histogram update: one atomic per distinct bin per wave
        unsigned int bin = sortable(v) >> 19;
        unsigned long long remm = __ballot(1);
        while (remm) {
            int leader = __ffsll((unsigned long long)remm) - 1;
            unsigned int lb = __shfl(bin, leader);
            unsigned long long eq = __ballot(bin == lb) & remm;
            if (lane == leader)
                atomicAdd(&lh[lb], (unsigned int)__popcll(eq));
            remm &= ~eq;
        }
    }
    __syncthreads();
    unsigned int* hb = hist1 + (size_t)b * NB1;
    for (int i = threadIdx.x; i < NB1; i += 256) {
        unsigned int c = lh[i];
        if (c) atomicAdd(&hb[i], c);
    }
}

// ---------------- parallel 8192-bin top-down selection (hist in global) ----------------
__device__ __forceinline__ void select_bin(const unsigned int* __restrict__ hb,
                                           int rem, int* bin_out, int* rem_out) {
    __shared__ unsigned int cs[256];
    __shared__ unsigned int bs[32];
    __shared__ int s_chunk, s_bin, s_rem;
    int t = threadIdx.x;
    unsigned int s = 0;
#pragma unroll 8
    for (int i = 0; i < 32; ++i) s += hb[t * 32 + i];
    cs[t] = s;
    __syncthreads();
    // Hillis-Steele inclusive suffix scan
    for (int d = 1; d < 256; d <<= 1) {
        unsigned int v = (t + d < 256) ? cs[t + d] : 0;
        __syncthreads();
        cs[t] += v;
        __syncthreads();
    }
    unsigned int St = cs[t];
    unsigned int St1 = (t < 255) ? cs[t + 1] : 0;
    if ((int)St >= rem && (t == 255 || (int)St1 < rem)) {
        s_chunk = t;
        s_rem = rem - (int)St1;
    }
    __syncthreads();
    int chunk = s_chunk;
    int rem2 = s_rem;
    if (t < 32) bs[t] = hb[chunk * 32 + t];
    __syncthreads();
    for (int d = 1; d < 32; d <<= 1) {
        unsigned int v = (t < 32 && t + d < 32) ? bs[t + d] : 0;
        __syncthreads();
        if (t < 32) bs[t] += v;
        __syncthreads();
    }
    if (t < 32) {
        unsigned int Sb = bs[t];
        unsigned int Sb1 = (t < 31) ? bs[t + 1] : 0;
        if ((int)Sb >= rem2 && (t == 31 || (int)Sb1 < rem2)) {
            s_bin = chunk * 32 + t;
            s_rem = rem2 - (int)Sb1;
        }
    }
    __syncthreads();
    *bin_out = s_bin;
    *rem_out = s_rem;
}

// ---------------- scan 1: coarse threshold bin ----------------
__global__ __launch_bounds__(256) void k_scan1(const unsigned int* __restrict__ hist1,
                                               unsigned int* __restrict__ T1,
                                               int* __restrict__ r1) {
    int b = blockIdx.x;
    int bin, rem;
    select_bin(hist1 + (size_t)b * NB1, KTOP, &bin, &rem);
    if (threadIdx.x == 0) { T1[b] = (unsigned int)bin; r1[b] = rem; }
}

// ---------------- pass-2: refine hist (counts + sums) + strict-above sum ----------------
__global__ __launch_bounds__(256) void k_hist2(const float4* __restrict__ score,
                                               const unsigned int* __restrict__ T1,
                                               unsigned int* __restrict__ hist2,
                                               float* __restrict__ hsum,
                                               float* __restrict__ out) {
    __shared__ unsigned int lh[NB1];
    __shared__ float ls[NB1];
    __shared__ float red[4];
    int b = blockIdx.x >> 7;
    int seg = blockIdx.x & (SEG - 1);
    for (int i = threadIdx.x; i < NB1; i += 256) { lh[i] = 0; ls[i] = 0.f; }
    __syncthreads();
    unsigned int t1 = T1[b];
    const float4* p = score + ((size_t)b * HW + (size_t)seg * (HW / SEG)) / 4;
    float sa = 0.f;   // sum of values strictly above the T1 coarse bin
    for (int i = threadIdx.x; i < (HW / SEG) / 4; i += 256) {
        float4 v = p[i];
        float vv[4] = {v.x, v.y, v.z, v.w};
#pragma unroll
        for (int q = 0; q < 4; ++q) {
            unsigned int k = sortable(vv[q]);
            unsigned int cb = k >> 19;
            if (cb > t1) sa += vv[q];
            else if (cb == t1) {
                int sub = (k >> 6) & 0x1FFF;
                atomicAdd(&lh[sub], 1u);
                atomicAdd(&ls[sub], vv[q]);
            }
        }
    }
    __syncthreads();
    unsigned int* hb = hist2 + (size_t)b * NB1;
    float* sb = hsum + (size_t)b * NB1;
    for (int i = threadIdx.x; i < NB1; i += 256) {
        unsigned int c = lh[i];
        if (c) { atomicAdd(&hb[i], c); atomicAdd(&sb[i], ls[i]); }
    }
    // block-reduce strict-above sum, one atomic per block
#pragma unroll
    for (int d = 32; d; d >>= 1) sa += __shfl_down(sa, d);
    if ((threadIdx.x & 63) == 0) red[threadIdx.x >> 6] = sa;
    __syncthreads();
    if (threadIdx.x == 0) {
        float tt = red[0] + red[1] + red[2] + red[3];
        if (tt != 0.f) atomicAdd(&out[b], tt);
    }
}

// ---------------- scan 2: final threshold + tail sums -> out ----------------
__global__ __launch_bounds__(256) void k_scan2(const unsigned int* __restrict__ hist2,
                                               const float* __restrict__ hsum,
                                               const unsigned int* __restrict__ T1,
                                               const int* __restrict__ r1,
                                               float* __restrict__ out) {
    int b = blockIdx.x;
    int bin, rem;
    select_bin(hist2 + (size_t)b * NB1, r1[b], &bin, &rem);
    __shared__ float rs[256];
    int t = threadIdx.x;
    const float* sb = hsum + (size_t)b * NB1;
    float s = 0.f;
    for (int i = t; i < NB1; i += 256) if (i > bin) s += sb[i];
    rs[t] = s;
    __syncthreads();
    for (int d = 128; d; d >>= 1) {
        if (t < d) rs[t] += rs[t + d];
        __syncthreads();
    }
    if (t == 0) {
        unsigned int K = (T1[b] << 19) | ((unsigned int)bin << 6);
        out[b] += rs[0] + unsortable(K) * (float)rem;   // ties at 26-bit bin edge
    }
}

extern "C" void kernel_launch(void* const* d_in, const int* in_sizes, int n_in,
                              void* d_out, int out_size, void* d_ws, size_t ws_size,
                              hipStream_t stream) {
    const float* logit = (const float*)d_in[0];
    float* out = (float*)d_out;
    char* ws = (char*)d_ws;

    // workspace layout
    float*         ent   = (float*)(ws);                           // 8,388,608 B
    unsigned char* pred  = (unsigned char*)(ws + 8388608);         // 2,097,152 B
    float*         score = (float*)(ws + 10485760);                // 8,388,608 B
    unsigned int*  histb = (unsigned int*)(ws + 18874368);
    unsigned int*  hist1 = histb;                                  // 32768 words
    unsigned int*  hist2 = histb + 32768;                          // 32768 words
    float*         hsum  = (float*)(histb + 65536);                // 32768 words
    unsigned int*  T1    = histb + 98304;                          // 4
    int*           r1    = (int*)(histb + 98308);                  // 4

    k_ent<<<BHW / 4 / 256, 256, 0, stream>>>((const float4*)logit, (float4*)ent,
                                             (uchar4*)pred, histb, out);
    k_score_hist<<<BB * SEG, 256, 0, stream>>>(ent, pred, score, hist1);
    k_scan1<<<BB, 256, 0, stream>>>(hist1, T1, r1);
    k_hist2<<<BB * SEG, 256, 0, stream>>>((const float4*)score, T1, hist2, hsum, out);
    k_scan2<<<BB, 256, 0, stream>>>(hist2, hsum, T1, r1, out);
}

// Round 6
// 305.180 us; speedup vs baseline: 1.0156x; 1.0156x over previous
//
#include <hip/hip_runtime.h>
#include <cstdint>
#include <cstddef>

#define BB 4
#define CC 19
#define HH 512
#define WW 1024
#define HW (HH*WW)          // 524288 = 2^19
#define BHW (BB*HW)
#define KTOP 256
#define EPSF 1e-6f
#define NB1 8192
#define SEG 128
#define TS 32
#define THALO 34
#define LOGC 2.9444389791664403f   // ln(19)

__device__ __forceinline__ unsigned int sortable(float x) {
    unsigned int u = __float_as_uint(x);
    return (u & 0x80000000u) ? ~u : (u | 0x80000000u);
}
__device__ __forceinline__ float unsortable(unsigned int K) {
    unsigned int u = (K & 0x80000000u) ? (K & 0x7FFFFFFFu) : ~K;
    return __uint_as_float(u);
}

// ------- Kernel 1: fused entropy+argmax (LDS halo tile) + score + hist1 -------
__global__ __launch_bounds__(256) void k_fused(const float* __restrict__ logit,
                                               float* __restrict__ score,
                                               unsigned int* __restrict__ hist1) {
    __shared__ float ent[THALO * THALO];
    __shared__ int prd[THALO * THALO];
    __shared__ unsigned int lh[NB1];
    int blk = blockIdx.x;
    int b = blk >> 9;                 // /512 tiles per image
    int tile = blk & 511;
    int ty = tile >> 5, tx = tile & 31;   // 16 x 32 tiles
    int h0 = ty * TS, w0 = tx * TS;

    for (int i = threadIdx.x; i < NB1; i += 256) lh[i] = 0;

    // phase 1: entropy + argmax for the 34x34 halo (OOB -> ent=0, cls=255)
    for (int k = 0; k < 5; ++k) {
        int p = threadIdx.x + k * 256;
        if (p < THALO * THALO) {
            int ly = p / THALO, lx = p - ly * THALO;
            int gy = h0 - 1 + ly, gx = w0 - 1 + lx;
            bool ok = (gy >= 0) & (gy < HH) & (gx >= 0) & (gx < WW);
            float e = 0.f; float m = -1.f; int am = 255;
            if (ok) {
                const float* base = logit + (size_t)b * CC * HW + gy * WW + gx;
                am = 0;
#pragma unroll
                for (int c = 0; c < CC; ++c) {
                    float pv = base[(size_t)c * HW];
                    e -= pv * __logf(pv + EPSF);
                    if (pv > m) { m = pv; am = c; }
                }
            }
            ent[p] = e;
            prd[p] = am;
        }
    }
    __syncthreads();

    // phase 2: score the 32x32 interior pixels (4 per thread)
    float* sbuf = score + (size_t)b * HW;
#pragma unroll
    for (int q = 0; q < 4; ++q) {
        int pix = threadIdx.x + q * 256;
        int py = pix >> 5, px = pix & 31;
        int h = h0 + py, w = w0 + px;
        int lbase = py * THALO + px;      // top-left of the 3x3 window
        float es = 0.f;
        int cls[9];
#pragma unroll
        for (int i = 0; i < 9; ++i) {
            int o = lbase + (i / 3) * THALO + (i % 3);
            es += ent[o];
            cls[i] = prd[o];
        }
        int nv = ((h > 0) + (h < HH - 1) + 1) * ((w > 0) + (w < WW - 1) + 1);
        float inv = 1.f / (float)nv;
        // branch-free impurity: -inv * sum_{i valid} ln(cnt_i*inv + eps)
        float lsum = 0.f;
#pragma unroll
        for (int i = 0; i < 9; ++i) {
            int cnt = 0;
#pragma unroll
            for (int j = 0; j < 9; ++j) cnt += (cls[j] == cls[i]) ? 1 : 0;
            float lg = __logf((float)cnt * inv + EPSF);
            lsum += (cls[i] != 255) ? lg : 0.f;
        }
        float imp = -inv * lsum;
        float v = (es * (1.f / (9.f * LOGC))) * (imp * (1.f / LOGC));
        sbuf[h * WW + w] = v;
        atomicAdd(&lh[sortable(v) >> 19], 1u);
    }
    __syncthreads();
    unsigned int* hb = hist1 + (size_t)b * NB1;
    for (int i = threadIdx.x; i < NB1; i += 256) {
        unsigned int c = lh[i];
        if (c) atomicAdd(&hb[i], c);
    }
}

// ---------------- parallel 8192-bin top-down selection (hist in global) ----------------
__device__ __forceinline__ void select_bin(const unsigned int* __restrict__ hb,
                                           int rem, int* bin_out, int* rem_out) {
    __shared__ unsigned int cs[256];
    __shared__ unsigned int bs[32];
    __shared__ int s_chunk, s_bin, s_rem;
    int t = threadIdx.x;
    unsigned int s = 0;
#pragma unroll 8
    for (int i = 0; i < 32; ++i) s += hb[t * 32 + i];
    cs[t] = s;
    __syncthreads();
    // Hillis-Steele inclusive suffix scan
    for (int d = 1; d < 256; d <<= 1) {
        unsigned int v = (t + d < 256) ? cs[t + d] : 0;
        __syncthreads();
        cs[t] += v;
        __syncthreads();
    }
    unsigned int St = cs[t];
    unsigned int St1 = (t < 255) ? cs[t + 1] : 0;
    if ((int)St >= rem && (t == 255 || (int)St1 < rem)) {
        s_chunk = t;
        s_rem = rem - (int)St1;
    }
    __syncthreads();
    int chunk = s_chunk;
    int rem2 = s_rem;
    if (t < 32) bs[t] = hb[chunk * 32 + t];
    __syncthreads();
    for (int d = 1; d < 32; d <<= 1) {
        unsigned int v = (t < 32 && t + d < 32) ? bs[t + d] : 0;
        __syncthreads();
        if (t < 32) bs[t] += v;
        __syncthreads();
    }
    if (t < 32) {
        unsigned int Sb = bs[t];
        unsigned int Sb1 = (t < 31) ? bs[t + 1] : 0;
        if ((int)Sb >= rem2 && (t == 31 || (int)Sb1 < rem2)) {
            s_bin = chunk * 32 + t;
            s_rem = rem2 - (int)Sb1;
        }
    }
    __syncthreads();
    *bin_out = s_bin;
    *rem_out = s_rem;
}

// ---------------- scan 1: coarse threshold bin ----------------
__global__ __launch_bounds__(256) void k_scan1(const unsigned int* __restrict__ hist1,
                                               unsigned int* __restrict__ T1,
                                               int* __restrict__ r1) {
    int b = blockIdx.x;
    int bin, rem;
    select_bin(hist1 + (size_t)b * NB1, KTOP, &bin, &rem);
    if (threadIdx.x == 0) { T1[b] = (unsigned int)bin; r1[b] = rem; }
}

// ---------------- pass-2: refine hist (counts + sums) + strict-above sum ----------------
__global__ __launch_bounds__(256) void k_hist2(const float4* __restrict__ score,
                                               const unsigned int* __restrict__ T1,
                                               unsigned int* __restrict__ hist2,
                                               float* __restrict__ hsum,
                                               float* __restrict__ out) {
    __shared__ unsigned int lh[NB1];
    __shared__ float ls[NB1];
    __shared__ float red[4];
    int b = blockIdx.x >> 7;
    int seg = blockIdx.x & (SEG - 1);
    for (int i = threadIdx.x; i < NB1; i += 256) { lh[i] = 0; ls[i] = 0.f; }
    __syncthreads();
    unsigned int t1 = T1[b];
    const float4* p = score + ((size_t)b * HW + (size_t)seg * (HW / SEG)) / 4;
    float sa = 0.f;   // sum of values strictly above the T1 coarse bin
    for (int i = threadIdx.x; i < (HW / SEG) / 4; i += 256) {
        float4 v = p[i];
        float vv[4] = {v.x, v.y, v.z, v.w};
#pragma unroll
        for (int q = 0; q < 4; ++q) {
            unsigned int k = sortable(vv[q]);
            unsigned int cb = k >> 19;
            if (cb > t1) sa += vv[q];
            else if (cb == t1) {
                int sub = (k >> 6) & 0x1FFF;
                atomicAdd(&lh[sub], 1u);
                atomicAdd(&ls[sub], vv[q]);
            }
        }
    }
    __syncthreads();
    unsigned int* hb = hist2 + (size_t)b * NB1;
    float* sb = hsum + (size_t)b * NB1;
    for (int i = threadIdx.x; i < NB1; i += 256) {
        unsigned int c = lh[i];
        if (c) { atomicAdd(&hb[i], c); atomicAdd(&sb[i], ls[i]); }
    }
    // block-reduce strict-above sum, one atomic per block
#pragma unroll
    for (int d = 32; d; d >>= 1) sa += __shfl_down(sa, d);
    if ((threadIdx.x & 63) == 0) red[threadIdx.x >> 6] = sa;
    __syncthreads();
    if (threadIdx.x == 0) {
        float tt = red[0] + red[1] + red[2] + red[3];
        if (tt != 0.f) atomicAdd(&out[b], tt);
    }
}

// ---------------- scan 2: final threshold + tail sums -> out ----------------
__global__ __launch_bounds__(256) void k_scan2(const unsigned int* __restrict__ hist2,
                                               const float* __restrict__ hsum,
                                               const unsigned int* __restrict__ T1,
                                               const int* __restrict__ r1,
                                               float* __restrict__ out) {
    int b = blockIdx.x;
    int bin, rem;
    select_bin(hist2 + (size_t)b * NB1, r1[b], &bin, &rem);
    __shared__ float rs[256];
    int t = threadIdx.x;
    const float* sb = hsum + (size_t)b * NB1;
    float s = 0.f;
    for (int i = t; i < NB1; i += 256) if (i > bin) s += sb[i];
    rs[t] = s;
    __syncthreads();
    for (int d = 128; d; d >>= 1) {
        if (t < d) rs[t] += rs[t + d];
        __syncthreads();
    }
    if (t == 0) {
        unsigned int K = (T1[b] << 19) | ((unsigned int)bin << 6);
        out[b] += rs[0] + unsortable(K) * (float)rem;   // ties at 26-bit bin edge
    }
}

extern "C" void kernel_launch(void* const* d_in, const int* in_sizes, int n_in,
                              void* d_out, int out_size, void* d_ws, size_t ws_size,
                              hipStream_t stream) {
    const float* logit = (const float*)d_in[0];
    float* out = (float*)d_out;
    char* ws = (char*)d_ws;

    // workspace layout
    float*         score = (float*)(ws);                           // 8,388,608 B
    unsigned int*  histb = (unsigned int*)(ws + 8388608);
    unsigned int*  hist1 = histb;                                  // 32768 words
    unsigned int*  hist2 = histb + 32768;                          // 32768 words
    float*         hsum  = (float*)(histb + 65536);                // 32768 words
    unsigned int*  T1    = histb + 98304;                          // 4
    int*           r1    = (int*)(histb + 98308);                  // 4

    hipMemsetAsync(histb, 0, 393248, stream);                      // hist1+hist2+hsum+scalars
    hipMemsetAsync(d_out, 0, (size_t)out_size * sizeof(float), stream);

    k_fused<<<BB * 512, 256, 0, stream>>>(logit, score, hist1);
    k_scan1<<<BB, 256, 0, stream>>>(hist1, T1, r1);
    k_hist2<<<BB * SEG, 256, 0, stream>>>((const float4*)score, T1, hist2, hsum, out);
    k_scan2<<<BB, 256, 0, stream>>>(hist2, hsum, T1, r1, out);
}

// Round 7
// 292.933 us; speedup vs baseline: 1.0581x; 1.0418x over previous
//
#include <hip/hip_runtime.h>
#include <cstdint>
#include <cstddef>

#define BB 4
#define CC 19
#define HH 512
#define WW 1024
#define HW (HH*WW)          // 524288 = 2^19
#define HW4 (HW/4)          // 131072 = 2^17
#define BHW (BB*HW)
#define KTOP 256
#define EPSF 1e-6f
#define NB1 8192
#define SEG 128
#define LOGC 2.9444389791664403f   // ln(19)

__device__ __forceinline__ unsigned int sortable(float x) {
    unsigned int u = __float_as_uint(x);
    return (u & 0x80000000u) ? ~u : (u | 0x80000000u);
}
__device__ __forceinline__ float unsortable(unsigned int K) {
    unsigned int u = (K & 0x80000000u) ? (K & 0x7FFFFFFFu) : ~K;
    return __uint_as_float(u);
}

// ---------------- Kernel 1: entropy + argmax + zero-init ----------------
__global__ __launch_bounds__(256) void k_ent(const float4* __restrict__ logit,
                                             float4* __restrict__ ent,
                                             uchar4* __restrict__ pred,
                                             unsigned int* __restrict__ histz,
                                             float* __restrict__ outz) {
    int idx = blockIdx.x * 256 + threadIdx.x;     // over BHW/4
    if (idx < 98312) histz[idx] = 0;              // hist1 + hist2 + hsum + scalars
    if (idx < BB) outz[idx] = 0.f;
    int b = idx >> 17;
    int q = idx & (HW4 - 1);
    const float4* base = logit + (size_t)b * CC * HW4 + q;
    float e0 = 0.f, e1 = 0.f, e2 = 0.f, e3 = 0.f;
    float m0 = -1.f, m1 = -1.f, m2 = -1.f, m3 = -1.f;
    int a0 = 0, a1 = 0, a2 = 0, a3 = 0;
#pragma unroll
    for (int c = 0; c < CC; ++c) {
        float4 p = base[(size_t)c * HW4];
        e0 -= p.x * __logf(p.x + EPSF); if (p.x > m0) { m0 = p.x; a0 = c; }
        e1 -= p.y * __logf(p.y + EPSF); if (p.y > m1) { m1 = p.y; a1 = c; }
        e2 -= p.z * __logf(p.z + EPSF); if (p.z > m2) { m2 = p.z; a2 = c; }
        e3 -= p.w * __logf(p.w + EPSF); if (p.w > m3) { m3 = p.w; a3 = c; }
    }
    ent[idx] = make_float4(e0, e1, e2, e3);
    pred[idx] = make_uchar4((unsigned char)a0, (unsigned char)a1,
                            (unsigned char)a2, (unsigned char)a3);
}

// ---------------- Kernel 2: score + LDS hist1; impurity logs via LUT ----------------
__global__ __launch_bounds__(256) void k_score_hist(const float* __restrict__ ent,
                                                    const unsigned char* __restrict__ pred,
                                                    float* __restrict__ score,
                                                    unsigned int* __restrict__ hist1) {
    __shared__ unsigned int lh[NB1];
    __shared__ float lgt[48];         // lgt[nvi*16+cnt] = ln(cnt/nv + eps), nv in {4,6,9}
    int b = blockIdx.x >> 7;          // / SEG
    int seg = blockIdx.x & (SEG - 1);
    for (int i = threadIdx.x; i < NB1; i += 256) lh[i] = 0;
    if (threadIdx.x < 48) {
        int nvi = threadIdx.x >> 4;
        int cnt = threadIdx.x & 15;
        float nv = (nvi == 0) ? 4.f : (nvi == 1) ? 6.f : 9.f;
        lgt[threadIdx.x] = __logf((float)cnt / nv + EPSF);
    }
    __syncthreads();
    const float* eb = ent + (size_t)b * HW;
    const unsigned char* pb = pred + (size_t)b * HW;
    int base = seg * (HW / SEG);      // 4096 pixels = 4 rows

    for (int it = 0; it < 16; ++it) {
        int hw = base + it * 256 + threadIdx.x;
        int h = hw >> 10;
        int w = hw & (WW - 1);

        float es = 0.f;
        int cls[9];
        int nv = 0;
#pragma unroll
        for (int i = 0; i < 9; ++i) {
            int dh = i / 3 - 1, dw = i % 3 - 1;
            int hh = h + dh, ww = w + dw;
            bool ok = (hh >= 0) & (hh < HH) & (ww >= 0) & (ww < WW);
            int o = ok ? ((hh << 10) | ww) : 0;
            es += ok ? eb[o] : 0.f;
            cls[i] = ok ? (int)pb[o] : 255;
            nv += ok ? 1 : 0;
        }
        float inv = 1.f / (float)nv;
        int nvi = (nv == 9) ? 2 : ((nv == 6) ? 1 : 0);
        const float* lg = &lgt[nvi * 16];
        // branch-free impurity via LUT: -inv * sum_{i valid} ln(cnt_i/nv + eps)
        float lsum = 0.f;
#pragma unroll
        for (int i = 0; i < 9; ++i) {
            int cnt = 0;
#pragma unroll
            for (int j = 0; j < 9; ++j) cnt += (cls[j] == cls[i]) ? 1 : 0;
            float lv = lg[cnt];
            lsum += (cls[i] != 255) ? lv : 0.f;
        }
        float imp = -inv * lsum;
        float v = (es * (1.f / (9.f * LOGC))) * (imp * (1.f / LOGC));
        score[(size_t)b * HW + hw] = v;
        atomicAdd(&lh[sortable(v) >> 19], 1u);
    }
    __syncthreads();
    unsigned int* hb = hist1 + (size_t)b * NB1;
    for (int i = threadIdx.x; i < NB1; i += 256) {
        unsigned int c = lh[i];
        if (c) atomicAdd(&hb[i], c);
    }
}

// ---------------- parallel 8192-bin top-down selection (hist in global) ----------------
__device__ __forceinline__ void select_bin(const unsigned int* __restrict__ hb,
                                           int rem, int* bin_out, int* rem_out) {
    __shared__ unsigned int cs[256];
    __shared__ unsigned int bs[32];
    __shared__ int s_chunk, s_bin, s_rem;
    int t = threadIdx.x;
    unsigned int s = 0;
#pragma unroll 8
    for (int i = 0; i < 32; ++i) s += hb[t * 32 + i];
    cs[t] = s;
    __syncthreads();
    // Hillis-Steele inclusive suffix scan
    for (int d = 1; d < 256; d <<= 1) {
        unsigned int v = (t + d < 256) ? cs[t + d] : 0;
        __syncthreads();
        cs[t] += v;
        __syncthreads();
    }
    unsigned int St = cs[t];
    unsigned int St1 = (t < 255) ? cs[t + 1] : 0;
    if ((int)St >= rem && (t == 255 || (int)St1 < rem)) {
        s_chunk = t;
        s_rem = rem - (int)St1;
    }
    __syncthreads();
    int chunk = s_chunk;
    int rem2 = s_rem;
    if (t < 32) bs[t] = hb[chunk * 32 + t];
    __syncthreads();
    for (int d = 1; d < 32; d <<= 1) {
        unsigned int v = (t < 32 && t + d < 32) ? bs[t + d] : 0;
        __syncthreads();
        if (t < 32) bs[t] += v;
        __syncthreads();
    }
    if (t < 32) {
        unsigned int Sb = bs[t];
        unsigned int Sb1 = (t < 31) ? bs[t + 1] : 0;
        if ((int)Sb >= rem2 && (t == 31 || (int)Sb1 < rem2)) {
            s_bin = chunk * 32 + t;
            s_rem = rem2 - (int)Sb1;
        }
    }
    __syncthreads();
    *bin_out = s_bin;
    *rem_out = s_rem;
}

// ---------------- scan 1: coarse threshold bin ----------------
__global__ __launch_bounds__(256) void k_scan1(const unsigned int* __restrict__ hist1,
                                               unsigned int* __restrict__ T1,
                                               int* __restrict__ r1) {
    int b = blockIdx.x;
    int bin, rem;
    select_bin(hist1 + (size_t)b * NB1, KTOP, &bin, &rem);
    if (threadIdx.x == 0) { T1[b] = (unsigned int)bin; r1[b] = rem; }
}

// ---------------- pass-2: refine hist (counts + sums) + strict-above sum ----------------
__global__ __launch_bounds__(256) void k_hist2(const float4* __restrict__ score,
                                               const unsigned int* __restrict__ T1,
                                               unsigned int* __restrict__ hist2,
                                               float* __restrict__ hsum,
                                               float* __restrict__ out) {
    __shared__ unsigned int lh[NB1];
    __shared__ float ls[NB1];
    __shared__ float red[4];
    int b = blockIdx.x >> 7;
    int seg = blockIdx.x & (SEG - 1);
    for (int i = threadIdx.x; i < NB1; i += 256) { lh[i] = 0; ls[i] = 0.f; }
    __syncthreads();
    unsigned int t1 = T1[b];
    const float4* p = score + ((size_t)b * HW + (size_t)seg * (HW / SEG)) / 4;
    float sa = 0.f;   // sum of values strictly above the T1 coarse bin
    for (int i = threadIdx.x; i < (HW / SEG) / 4; i += 256) {
        float4 v = p[i];
        float vv[4] = {v.x, v.y, v.z, v.w};
#pragma unroll
        for (int q = 0; q < 4; ++q) {
            unsigned int k = sortable(vv[q]);
            unsigned int cb = k >> 19;
            if (cb > t1) sa += vv[q];
            else if (cb == t1) {
                int sub = (k >> 6) & 0x1FFF;
                atomicAdd(&lh[sub], 1u);
                atomicAdd(&ls[sub], vv[q]);
            }
        }
    }
    __syncthreads();
    unsigned int* hb = hist2 + (size_t)b * NB1;
    float* sb = hsum + (size_t)b * NB1;
    for (int i = threadIdx.x; i < NB1; i += 256) {
        unsigned int c = lh[i];
        if (c) { atomicAdd(&hb[i], c); atomicAdd(&sb[i], ls[i]); }
    }
    // block-reduce strict-above sum, one atomic per block
#pragma unroll
    for (int d = 32; d; d >>= 1) sa += __shfl_down(sa, d);
    if ((threadIdx.x & 63) == 0) red[threadIdx.x >> 6] = sa;
    __syncthreads();
    if (threadIdx.x == 0) {
        float tt = red[0] + red[1] + red[2] + red[3];
        if (tt != 0.f) atomicAdd(&out[b], tt);
    }
}

// ---------------- scan 2: final threshold + tail sums -> out ----------------
__global__ __launch_bounds__(256) void k_scan2(const unsigned int* __restrict__ hist2,
                                               const float* __restrict__ hsum,
                                               const unsigned int* __restrict__ T1,
                                               const int* __restrict__ r1,
                                               float* __restrict__ out) {
    int b = blockIdx.x;
    int bin, rem;
    select_bin(hist2 + (size_t)b * NB1, r1[b], &bin, &rem);
    __shared__ float rs[256];
    int t = threadIdx.x;
    const float* sb = hsum + (size_t)b * NB1;
    float s = 0.f;
    for (int i = t; i < NB1; i += 256) if (i > bin) s += sb[i];
    rs[t] = s;
    __syncthreads();
    for (int d = 128; d; d >>= 1) {
        if (t < d) rs[t] += rs[t + d];
        __syncthreads();
    }
    if (t == 0) {
        unsigned int K = (T1[b] << 19) | ((unsigned int)bin << 6);
        out[b] += rs[0] + unsortable(K) * (float)rem;   // ties at 26-bit bin edge
    }
}

extern "C" void kernel_launch(void* const* d_in, const int* in_sizes, int n_in,
                              void* d_out, int out_size, void* d_ws, size_t ws_size,
                              hipStream_t stream) {
    const float* logit = (const float*)d_in[0];
    float* out = (float*)d_out;
    char* ws = (char*)d_ws;

    // workspace layout
    float*         ent   = (float*)(ws);                           // 8,388,608 B
    unsigned char* pred  = (unsigned char*)(ws + 8388608);         // 2,097,152 B
    float*         score = (float*)(ws + 10485760);                // 8,388,608 B
    unsigned int*  histb = (unsigned int*)(ws + 18874368);
    unsigned int*  hist1 = histb;                                  // 32768 words
    unsigned int*  hist2 = histb + 32768;                          // 32768 words
    float*         hsum  = (float*)(histb + 65536);                // 32768 words
    unsigned int*  T1    = histb + 98304;                          // 4
    int*           r1    = (int*)(histb + 98308);                  // 4

    k_ent<<<BHW / 4 / 256, 256, 0, stream>>>((const float4*)logit, (float4*)ent,
                                             (uchar4*)pred, histb, out);
    k_score_hist<<<BB * SEG, 256, 0, stream>>>(ent, pred, score, hist1);
    k_scan1<<<BB, 256, 0, stream>>>(hist1, T1, r1);
    k_hist2<<<BB * SEG, 256, 0, stream>>>((const float4*)score, T1, hist2, hsum, out);
    k_scan2<<<BB, 256, 0, stream>>>(hist2, hsum, T1, r1, out);
}

// Round 8
// 288.166 us; speedup vs baseline: 1.0756x; 1.0165x over previous
//
#include <hip/hip_runtime.h>
#include <cstdint>
#include <cstddef>

#define BB 4
#define CC 19
#define HH 512
#define WW 1024
#define HW (HH*WW)          // 524288
#define HW4 (HW/4)          // 131072
#define BHW (BB*HW)
#define KTOP 256
#define EPSF 1e-6f
#define NB1 4096            // coarse bins: key >> 20
#define NB2 8192            // refine bins: (key >> 7) & 0x1FFF
#define SEG 128
#define LSTRIDE 1032        // padded LDS row stride (floats/bytes), data at col 4..1027
#define LOGC 2.9444389791664403f   // ln(19)

__device__ __forceinline__ unsigned int sortable(float x) {
    unsigned int u = __float_as_uint(x);
    return (u & 0x80000000u) ? ~u : (u | 0x80000000u);
}
__device__ __forceinline__ float unsortable(unsigned int K) {
    unsigned int u = (K & 0x80000000u) ? (K & 0x7FFFFFFFu) : ~K;
    return __uint_as_float(u);
}

// ---------------- Kernel 1: entropy + argmax + zero-init ----------------
__global__ __launch_bounds__(256) void k_ent(const float4* __restrict__ logit,
                                             float4* __restrict__ ent,
                                             uchar4* __restrict__ pred,
                                             unsigned int* __restrict__ histz,
                                             float* __restrict__ outz) {
    int idx = blockIdx.x * 256 + threadIdx.x;     // over BHW/4
    if (idx < 81928) histz[idx] = 0;              // hist1+hist2+hsum+scalars
    if (idx < BB) outz[idx] = 0.f;
    int b = idx >> 17;
    int q = idx & (HW4 - 1);
    const float4* base = logit + (size_t)b * CC * HW4 + q;
    float e0 = 0.f, e1 = 0.f, e2 = 0.f, e3 = 0.f;
    float m0 = -1.f, m1 = -1.f, m2 = -1.f, m3 = -1.f;
    int a0 = 0, a1 = 0, a2 = 0, a3 = 0;
#pragma unroll
    for (int c = 0; c < CC; ++c) {
        float4 p = base[(size_t)c * HW4];
        e0 -= p.x * __logf(p.x + EPSF); if (p.x > m0) { m0 = p.x; a0 = c; }
        e1 -= p.y * __logf(p.y + EPSF); if (p.y > m1) { m1 = p.y; a1 = c; }
        e2 -= p.z * __logf(p.z + EPSF); if (p.z > m2) { m2 = p.z; a2 = c; }
        e3 -= p.w * __logf(p.w + EPSF); if (p.w > m3) { m3 = p.w; a3 = c; }
    }
    ent[idx] = make_float4(e0, e1, e2, e3);
    pred[idx] = make_uchar4((unsigned char)a0, (unsigned char)a1,
                            (unsigned char)a2, (unsigned char)a3);
}

// ------- Kernel 2: score + coarse hist; ent/pred rows staged in LDS -------
__global__ __launch_bounds__(256) void k_score_hist(const float* __restrict__ ent,
                                                    const unsigned char* __restrict__ pred,
                                                    float* __restrict__ score,
                                                    unsigned int* __restrict__ hist1) {
    __shared__ __align__(16) float ent_s[6 * LSTRIDE];
    __shared__ __align__(16) unsigned char pred_s[6 * LSTRIDE];
    __shared__ unsigned int lh[NB1];
    __shared__ float lgt[48];         // lgt[nvi*16+cnt] = ln(cnt/nv + eps), nv in {4,6,9}
    int tid = threadIdx.x;
    int b = blockIdx.x >> 7;          // / SEG
    int seg = blockIdx.x & (SEG - 1);
    int r0 = seg * 4;                 // 4 output rows per block

    for (int i = tid; i < 6 * LSTRIDE; i += 256) { ent_s[i] = 0.f; pred_s[i] = 255; }
    for (int i = tid; i < NB1; i += 256) lh[i] = 0;
    if (tid < 48) {
        int nvi = tid >> 4, cnt = tid & 15;
        float nv = (nvi == 0) ? 4.f : (nvi == 1) ? 6.f : 9.f;
        lgt[tid] = __logf((float)cnt / nv + EPSF);
    }
    __syncthreads();

    const float* eb = ent + (size_t)b * HW;
    const unsigned char* pb = pred + (size_t)b * HW;
    // stage 6 rows (r0-1 .. r0+4), coalesced float4/uchar4
    for (int i = tid; i < 1536; i += 256) {       // 6 rows x 256 quads
        int rr = i >> 8, c4 = i & 255;
        int g = r0 - 1 + rr;
        if (g >= 0 && g < HH) {
            float4 v = *(const float4*)(eb + g * WW + c4 * 4);
            *(float4*)&ent_s[rr * LSTRIDE + 4 + c4 * 4] = v;
            uchar4 pv = *(const uchar4*)(pb + g * WW + c4 * 4);
            *(uchar4*)&pred_s[rr * LSTRIDE + 4 + c4 * 4] = pv;
        }
    }
    __syncthreads();

    float* sbuf = score + (size_t)b * HW;
#pragma unroll
    for (int it = 0; it < 16; ++it) {
        int p = it * 256 + tid;       // 0..4095
        int py = p >> 10, px = p & 1023;
        int h = r0 + py, w = px;
        int l0 = py * LSTRIDE + 3 + px;   // LDS row py = global h-1; col = w-1
        float es = 0.f;
        int cls[9];
#pragma unroll
        for (int i = 0; i < 9; ++i) {
            int o = l0 + (i / 3) * LSTRIDE + (i % 3);
            es += ent_s[o];
            cls[i] = pred_s[o];
        }
        int nv = ((h > 0) + (h < HH - 1) + 1) * ((w > 0) + (w < WW - 1) + 1);
        float inv = 1.f / (float)nv;
        int nvi = (nv == 9) ? 2 : ((nv == 6) ? 1 : 0);
        const float* lg = &lgt[nvi * 16];
        float lsum = 0.f;
#pragma unroll
        for (int i = 0; i < 9; ++i) {
            int cnt = 0;
#pragma unroll
            for (int j = 0; j < 9; ++j) cnt += (cls[j] == cls[i]) ? 1 : 0;
            float lv = lg[cnt];
            lsum += (cls[i] != 255) ? lv : 0.f;
        }
        float imp = -inv * lsum;
        float v = (es * (1.f / (9.f * LOGC))) * (imp * (1.f / LOGC));
        sbuf[h * WW + w] = v;
        atomicAdd(&lh[sortable(v) >> 20], 1u);
    }
    __syncthreads();
    unsigned int* hb = hist1 + (size_t)b * NB1;
    for (int i = tid; i < NB1; i += 256) {
        unsigned int c = lh[i];
        if (c) atomicAdd(&hb[i], c);
    }
}

// ------- parallel 4096-bin top-down selection (hist in global/L2) -------
__device__ __forceinline__ void select4k(const unsigned int* __restrict__ hb,
                                         int rem, int* bin_out, int* rem_out) {
    __shared__ unsigned int cs[256];
    __shared__ unsigned int bs[16];
    __shared__ int s_chunk, s_bin, s_rem;
    int t = threadIdx.x;
    unsigned int s = 0;
#pragma unroll
    for (int i = 0; i < 16; ++i) s += hb[t * 16 + i];
    cs[t] = s;
    __syncthreads();
    for (int d = 1; d < 256; d <<= 1) {           // suffix scan
        unsigned int v = (t + d < 256) ? cs[t + d] : 0;
        __syncthreads();
        cs[t] += v;
        __syncthreads();
    }
    unsigned int St = cs[t];
    unsigned int St1 = (t < 255) ? cs[t + 1] : 0;
    if ((int)St >= rem && (t == 255 || (int)St1 < rem)) {
        s_chunk = t; s_rem = rem - (int)St1;
    }
    __syncthreads();
    int chunk = s_chunk, rem2 = s_rem;
    if (t < 16) bs[t] = hb[chunk * 16 + t];
    __syncthreads();
    for (int d = 1; d < 16; d <<= 1) {
        unsigned int v = (t < 16 && t + d < 16) ? bs[t + d] : 0;
        __syncthreads();
        if (t < 16) bs[t] += v;
        __syncthreads();
    }
    if (t < 16) {
        unsigned int Sb = bs[t];
        unsigned int Sb1 = (t < 15) ? bs[t + 1] : 0;
        if ((int)Sb >= rem2 && (t == 15 || (int)Sb1 < rem2)) {
            s_bin = chunk * 16 + t; s_rem = rem2 - (int)Sb1;
        }
    }
    __syncthreads();
    *bin_out = s_bin;
    *rem_out = s_rem;
}

// ------- parallel 8192-bin top-down selection -------
__device__ __forceinline__ void select8k(const unsigned int* __restrict__ hb,
                                         int rem, int* bin_out, int* rem_out) {
    __shared__ unsigned int cs[256];
    __shared__ unsigned int bs[32];
    __shared__ int s_chunk, s_bin, s_rem;
    int t = threadIdx.x;
    unsigned int s = 0;
#pragma unroll 8
    for (int i = 0; i < 32; ++i) s += hb[t * 32 + i];
    cs[t] = s;
    __syncthreads();
    for (int d = 1; d < 256; d <<= 1) {
        unsigned int v = (t + d < 256) ? cs[t + d] : 0;
        __syncthreads();
        cs[t] += v;
        __syncthreads();
    }
    unsigned int St = cs[t];
    unsigned int St1 = (t < 255) ? cs[t + 1] : 0;
    if ((int)St >= rem && (t == 255 || (int)St1 < rem)) {
        s_chunk = t; s_rem = rem - (int)St1;
    }
    __syncthreads();
    int chunk = s_chunk, rem2 = s_rem;
    if (t < 32) bs[t] = hb[chunk * 32 + t];
    __syncthreads();
    for (int d = 1; d < 32; d <<= 1) {
        unsigned int v = (t < 32 && t + d < 32) ? bs[t + d] : 0;
        __syncthreads();
        if (t < 32) bs[t] += v;
        __syncthreads();
    }
    if (t < 32) {
        unsigned int Sb = bs[t];
        unsigned int Sb1 = (t < 31) ? bs[t + 1] : 0;
        if ((int)Sb >= rem2 && (t == 31 || (int)Sb1 < rem2)) {
            s_bin = chunk * 32 + t; s_rem = rem2 - (int)Sb1;
        }
    }
    __syncthreads();
    *bin_out = s_bin;
    *rem_out = s_rem;
}

// ------- pass-2: per-block coarse select + refine hist + strict-above sum -------
__global__ __launch_bounds__(256) void k_hist2(const float4* __restrict__ score,
                                               const unsigned int* __restrict__ hist1,
                                               unsigned int* __restrict__ hist2,
                                               float* __restrict__ hsum,
                                               unsigned int* __restrict__ T1g,
                                               int* __restrict__ r1g,
                                               float* __restrict__ out) {
    __shared__ unsigned int lh[NB2];
    __shared__ float ls[NB2];
    __shared__ float red[4];
    int b = blockIdx.x >> 7;
    int seg = blockIdx.x & (SEG - 1);
    int bin1, rem1;
    select4k(hist1 + (size_t)b * NB1, KTOP, &bin1, &rem1);   // every block, hot L2
    unsigned int t1 = (unsigned int)bin1;
    if (seg == 0 && threadIdx.x == 0) { T1g[b] = t1; r1g[b] = rem1; }
    for (int i = threadIdx.x; i < NB2; i += 256) { lh[i] = 0; ls[i] = 0.f; }
    __syncthreads();
    const float4* p = score + ((size_t)b * HW + (size_t)seg * (HW / SEG)) / 4;
    float sa = 0.f;   // sum of values strictly above the T1 coarse bin
    for (int i = threadIdx.x; i < (HW / SEG) / 4; i += 256) {
        float4 v = p[i];
        float vv[4] = {v.x, v.y, v.z, v.w};
#pragma unroll
        for (int q = 0; q < 4; ++q) {
            unsigned int k = sortable(vv[q]);
            unsigned int cb = k >> 20;
            if (cb > t1) sa += vv[q];
            else if (cb == t1) {
                int sub = (k >> 7) & 0x1FFF;
                atomicAdd(&lh[sub], 1u);
                atomicAdd(&ls[sub], vv[q]);
            }
        }
    }
    __syncthreads();
    unsigned int* hb = hist2 + (size_t)b * NB2;
    float* sb = hsum + (size_t)b * NB2;
    for (int i = threadIdx.x; i < NB2; i += 256) {
        unsigned int c = lh[i];
        if (c) { atomicAdd(&hb[i], c); atomicAdd(&sb[i], ls[i]); }
    }
#pragma unroll
    for (int d = 32; d; d >>= 1) sa += __shfl_down(sa, d);
    if ((threadIdx.x & 63) == 0) red[threadIdx.x >> 6] = sa;
    __syncthreads();
    if (threadIdx.x == 0) {
        float tt = red[0] + red[1] + red[2] + red[3];
        if (tt != 0.f) atomicAdd(&out[b], tt);
    }
}

// ------- scan 2: final threshold + tail sums -> out -------
__global__ __launch_bounds__(256) void k_scan2(const unsigned int* __restrict__ hist2,
                                               const float* __restrict__ hsum,
                                               const unsigned int* __restrict__ T1g,
                                               const int* __restrict__ r1g,
                                               float* __restrict__ out) {
    int b = blockIdx.x;
    int bin, rem;
    select8k(hist2 + (size_t)b * NB2, r1g[b], &bin, &rem);
    __shared__ float rs[256];
    int t = threadIdx.x;
    const float* sb = hsum + (size_t)b * NB2;
    float s = 0.f;
    for (int i = t; i < NB2; i += 256) if (i > bin) s += sb[i];
    rs[t] = s;
    __syncthreads();
    for (int d = 128; d; d >>= 1) {
        if (t < d) rs[t] += rs[t + d];
        __syncthreads();
    }
    if (t == 0) {
        unsigned int K = (T1g[b] << 20) | ((unsigned int)bin << 7);
        out[b] += rs[0] + unsortable(K) * (float)rem;   // ties at 25-bit bin edge
    }
}

extern "C" void kernel_launch(void* const* d_in, const int* in_sizes, int n_in,
                              void* d_out, int out_size, void* d_ws, size_t ws_size,
                              hipStream_t stream) {
    const float* logit = (const float*)d_in[0];
    float* out = (float*)d_out;
    char* ws = (char*)d_ws;

    // workspace layout
    float*         ent   = (float*)(ws);                           // 8,388,608 B
    unsigned char* pred  = (unsigned char*)(ws + 8388608);         // 2,097,152 B
    float*         score = (float*)(ws + 10485760);                // 8,388,608 B
    unsigned int*  histb = (unsigned int*)(ws + 18874368);
    unsigned int*  hist1 = histb;                                  // 4*4096  = 16384 words
    unsigned int*  hist2 = histb + 16384;                          // 4*8192  = 32768 words
    float*         hsum  = (float*)(histb + 49152);                // 32768 words
    unsigned int*  T1g   = histb + 81920;                          // 4
    int*           r1g   = (int*)(histb + 81924);                  // 4

    k_ent<<<BHW / 4 / 256, 256, 0, stream>>>((const float4*)logit, (float4*)ent,
                                             (uchar4*)pred, histb, out);
    k_score_hist<<<BB * SEG, 256, 0, stream>>>(ent, pred, score, hist1);
    k_hist2<<<BB * SEG, 256, 0, stream>>>((const float4*)score, hist1,
                                          hist2, hsum, T1g, r1g, out);
    k_scan2<<<BB, 256, 0, stream>>>(hist2, hsum, T1g, r1g, out);
}